// Round 5
// baseline (384.948 us; speedup 1.0000x reference)
//
#include <hip/hip_runtime.h>
#include <hip/hip_bf16.h>
#include <stdint.h>
#include <stddef.h>

// SelfAttention: B=4 T=2048 E=1024 H=16 S=64, causal, q/k LayerNorm over S.
// f32 in/out; bf16 MFMA compute.
//   0) cvt_all: Wq/Wk/Wv/Wu and x f32 -> bf16 (one pass).
//   1) gemm_qkv: Q/K/V = x@W^T, fused head-LayerNorm (q,k), SCALE folded in Q.
//      m97 structure: global_load_lds width-16 staging, 128x128 tile, BK=32.
//   2) flash: causal attention with STATIC softmax: LN bounds give
//      |s*log2e| <= 11.7, so P = exp2(s*C - 12) needs no running max, no
//      alpha rescale, no per-tile reductions (l-sum deferred to epilogue).
//      64-row q-tiles, balanced pairs (p,31-p) -> 33 k-tiles/block,
//      grid 16x64=1024 blocks = 4 blocks/CU.  Output aliases Qb.
//   3) gemm_bias: out = attn@Wu^T + bu (same m97 structure).
// Workspace: Q(=AO),K,V (48MB) + W bf16 (8MB) + xb (16MB) = 72MB (fallback
// template if ws_size < 72MB keeps the old f32-A staging).

using bf16 = __hip_bfloat16;
typedef __attribute__((ext_vector_type(8))) short s16x8;
typedef __attribute__((ext_vector_type(4))) short s16x4;
typedef __attribute__((ext_vector_type(4))) float f32x4;

#define MFMA16(a, b, c) __builtin_amdgcn_mfma_f32_16x16x32_bf16((a), (b), (c), 0, 0, 0)

static __device__ __forceinline__ s16x8 ld8(const bf16* p) {
    return *reinterpret_cast<const s16x8*>(p);
}
static __device__ __forceinline__ s16x8 ld8s(const short* p) {
    return *reinterpret_cast<const s16x8*>(p);
}
static __device__ __forceinline__ s16x8 cvt8(const float* p) {
    f32x4 u = *reinterpret_cast<const f32x4*>(p);
    f32x4 v = *reinterpret_cast<const f32x4*>(p + 4);
    s16x8 r;
#pragma unroll
    for (int e = 0; e < 4; e++) {
        r[e]     = __builtin_bit_cast(short, __float2bfloat16(u[e]));
        r[e + 4] = __builtin_bit_cast(short, __float2bfloat16(v[e]));
    }
    return r;
}

// async global(bf16)->LDS, 16B per lane; lds base must be wave-uniform.
static __device__ __forceinline__ void async16(short* lds, const bf16* g) {
    __builtin_amdgcn_global_load_lds(
        (const __attribute__((address_space(1))) unsigned int*)g,
        (__attribute__((address_space(3))) unsigned int*)lds, 16, 0, 0);
}

#define EE 1024

// ---------------------------------------------------------------------------
// f32 -> bf16: z=0..3 weights (1M each), z=4..11 x slices (8 x 1M)
// ---------------------------------------------------------------------------
__global__ __launch_bounds__(256) void cvt_all(
    const float* __restrict__ w0, const float* __restrict__ w1,
    const float* __restrict__ w2, const float* __restrict__ w3,
    const float* __restrict__ x,
    bf16* __restrict__ o0, bf16* __restrict__ o1,
    bf16* __restrict__ o2, bf16* __restrict__ o3, bf16* __restrict__ xb)
{
    const int z = blockIdx.z;
    const float* s;
    bf16* d;
    if (z < 4) {
        s = (z == 0) ? w0 : (z == 1) ? w1 : (z == 2) ? w2 : w3;
        d = (z == 0) ? o0 : (z == 1) ? o1 : (z == 2) ? o2 : o3;
    } else {
        s = x  + (size_t)(z - 4) * 1048576;
        d = xb + (size_t)(z - 4) * 1048576;
    }
    size_t i = ((size_t)blockIdx.x * 256 + threadIdx.x) * 8;
    *reinterpret_cast<s16x8*>(d + i) = cvt8(s + i);
}

// ---------------------------------------------------------------------------
// Fused QKV GEMM + head LayerNorm.  z=0:Q(+LN,*0.125) z=1:K(+LN) z=2:V
// AF32=0: A staged via global_load_lds from xb.  AF32=1: f32 cvt fallback.
// ---------------------------------------------------------------------------
template <int AF32>
__global__ __launch_bounds__(256) void gemm_qkv_t(
    const float* __restrict__ xf, const bf16* __restrict__ xb,
    const bf16* __restrict__ Wq, const bf16* __restrict__ Wk, const bf16* __restrict__ Wv,
    bf16* __restrict__ Qb, bf16* __restrict__ Kb, bf16* __restrict__ Vb,
    const float* __restrict__ qg, const float* __restrict__ qbt,
    const float* __restrict__ kg, const float* __restrict__ kbt)
{
    constexpr int SA = AF32 ? 40 : 32;   // A-tile LDS stride (pad only in fallback)
    const int z = blockIdx.z;
    const bf16* Bt = (z == 0) ? Wq : (z == 1) ? Wk : Wv;
    bf16* out      = (z == 0) ? Qb : (z == 1) ? Kb : Vb;
    const float* gamma = (z == 0) ? qg : kg;
    const float* beta  = (z == 0) ? qbt : kbt;
    const bool  ln     = (z < 2);
    const float oscale = (z == 0) ? 0.125f : 1.0f;

    __shared__ __align__(16) short lA[128 * SA];
    __shared__ __align__(16) short lB[128 * 32];

    const int tid  = threadIdx.x;
    const int lane = tid & 63;
    const int w    = tid >> 6;
    const int wr = w >> 1, wc = w & 1;
    const int lr = lane & 15, quad = lane >> 4;

    const int m0 = blockIdx.y * 128;
    const int n0 = blockIdx.x * 128;

    const int strow = w * 32 + (lane >> 2);
    const int stcol = (lane & 3) * 8;
    const bf16* bgl = Bt + (size_t)(n0 + strow) * EE + stcol;
    short* bl = lB + (w * 2) * 512;

    const bf16* agl = nullptr;
    const float* ap = nullptr;
    short* al = lA + (w * 2) * 512;
    short* lap = nullptr;
    if constexpr (AF32) {
        const int sr  = tid >> 1;
        const int sc0 = (tid & 1) << 4;
        ap  = xf + (size_t)(m0 + sr) * EE + sc0;
        lap = lA + sr * SA + sc0;
    } else {
        agl = xb + (size_t)(m0 + strow) * EE + stcol;
    }

    f32x4 acc[4][4];
#pragma unroll
    for (int i = 0; i < 4; i++)
#pragma unroll
        for (int j = 0; j < 4; j++) acc[i][j] = (f32x4){0.f, 0.f, 0.f, 0.f};

    const short* lArd = lA + (wr * 64 + lr) * SA + quad * 8;
    const short* lBrd = lB + (wc * 64 + lr) * 32 + quad * 8;

    for (int kt = 0; kt < EE / 32; ++kt) {
        if constexpr (AF32) {
            s16x8 a0 = cvt8(ap), a1 = cvt8(ap + 8);
            __syncthreads();
            *reinterpret_cast<s16x8*>(lap)     = a0;
            *reinterpret_cast<s16x8*>(lap + 8) = a1;
            async16(bl, bgl);
            async16(bl + 512, bgl + 16 * EE);
            ap += 32;
        } else {
            __syncthreads();
            async16(al, agl);
            async16(al + 512, agl + 16 * EE);
            async16(bl, bgl);
            async16(bl + 512, bgl + 16 * EE);
            agl += 32;
        }
        bgl += 32;
        __syncthreads();

        s16x8 af[4], bfr[4];
#pragma unroll
        for (int i = 0; i < 4; i++) af[i]  = ld8s(lArd + i * 16 * SA);
#pragma unroll
        for (int j = 0; j < 4; j++) bfr[j] = ld8s(lBrd + j * 16 * 32);
#pragma unroll
        for (int i = 0; i < 4; i++)
#pragma unroll
            for (int j = 0; j < 4; j++) acc[i][j] = MFMA16(af[i], bfr[j], acc[i][j]);
    }

    if (ln) {
        float g[4], bt[4];
#pragma unroll
        for (int j = 0; j < 4; j++) {
            g[j]  = gamma[j * 16 + lr];
            bt[j] = beta[j * 16 + lr];
        }
#pragma unroll
        for (int i = 0; i < 4; i++) {
#pragma unroll
            for (int r = 0; r < 4; r++) {
                float s1 = 0.f, s2 = 0.f;
#pragma unroll
                for (int j = 0; j < 4; j++) {
                    float v = acc[i][j][r];
                    s1 += v;
                    s2 += v * v;
                }
#pragma unroll
                for (int off = 1; off < 16; off <<= 1) {
                    s1 += __shfl_xor(s1, off);
                    s2 += __shfl_xor(s2, off);
                }
                float mu  = s1 * (1.f / 64.f);
                float var = s2 * (1.f / 64.f) - mu * mu;
                float rs  = rsqrtf(var + 1e-5f);
                int row = m0 + wr * 64 + i * 16 + quad * 4 + r;
#pragma unroll
                for (int j = 0; j < 4; j++) {
                    float v = ((acc[i][j][r] - mu) * rs * g[j] + bt[j]) * oscale;
                    out[(size_t)row * EE + n0 + wc * 64 + j * 16 + lr] = __float2bfloat16(v);
                }
            }
        }
    } else {
#pragma unroll
        for (int i = 0; i < 4; i++)
#pragma unroll
            for (int r = 0; r < 4; r++) {
                int row = m0 + wr * 64 + i * 16 + quad * 4 + r;
#pragma unroll
                for (int j = 0; j < 4; j++)
                    out[(size_t)row * EE + n0 + wc * 64 + j * 16 + lr] =
                        __float2bfloat16(acc[i][j][r]);
            }
    }
}

// ---------------------------------------------------------------------------
// Causal flash attention, static softmax.
// grid = (16 pairs, 64 b*h); block = 4 waves; wave owns 16 q-rows.
// Block handles 64-row q-tiles {p, 31-p} -> exactly 33 k-tiles.
// Scores include 1/sqrt(S) via Q; |s*log2e| <= 11.7 (LN bound) -> M0=12.
// ---------------------------------------------------------------------------
__global__ __launch_bounds__(256, 4) void flash(
    const bf16* __restrict__ Qb, const bf16* __restrict__ Kb,
    const bf16* __restrict__ Vb, bf16* __restrict__ Ob)
{
    const int pr = blockIdx.x;
    const int bh = blockIdx.y;
    const int b = bh >> 4, h = bh & 15;
    const int tid = threadIdx.x, lane = tid & 63, w = tid >> 6;
    const int lr = lane & 15, quad = lane >> 4;
    const size_t base = (size_t)b * 2048 * 1024 + h * 64;
    const float C  = 1.44269504088896340736f;   // log2(e); 1/8 folded into Q
    const float M0 = 12.0f;                     // static max bound

    __shared__ __align__(16) short VT[64 * 72];   // V^T tile [s][key]
    __shared__ __align__(16) short PT[64 * 72];   // P tile   [query][key]

#pragma unroll 1
    for (int ph = 0; ph < 2; ++ph) {
        const int qt = ph ? (31 - pr) : pr;     // 64-row q-tile index
        const int tw = qt * 64 + w * 16;
        const int qq = tw + lr;                 // this lane's query row

        // Q fragments (B operand: col=query=lr, k=quad*8)
        s16x8 qf[2];
#pragma unroll
        for (int ks = 0; ks < 2; ks++)
            qf[ks] = ld8(Qb + base + (size_t)qq * 1024 + ks * 32 + quad * 8);

        f32x4 o[4];
#pragma unroll
        for (int j = 0; j < 4; j++) o[j] = (f32x4){0.f, 0.f, 0.f, 0.f};
        float lsum = 0.f;

        const int nkt = qt + 1;
        for (int kt = 0; kt < nkt; ++kt) {
            const int kb = kt * 64;

            // V tile: lane=key, wave=s-group (conflict-free VT writes)
            s16x8 v0 = ld8(Vb + base + (size_t)(kb + lane) * 1024 + w * 8);
            s16x8 v1 = ld8(Vb + base + (size_t)(kb + lane) * 1024 + w * 8 + 32);

            // K fragments (A operand: row=key=lr, k=quad*8)
            s16x8 kf[4][2];
#pragma unroll
            for (int jk = 0; jk < 4; jk++)
#pragma unroll
                for (int ks = 0; ks < 2; ks++)
                    kf[jk][ks] = ld8(Kb + base + (size_t)(kb + jk * 16 + lr) * 1024 +
                                     ks * 32 + quad * 8);

            __syncthreads();   // prior iter's VT/PT reads done
#pragma unroll
            for (int e = 0; e < 8; e++) {
                VT[(w * 8 + e) * 72 + lane]      = v0[e];
                VT[(w * 8 + 32 + e) * 72 + lane] = v1[e];
            }

            // S^T = K*Q^T: row=key=quad*4+r (subtile jk), col=query=lr
            f32x4 sc[4];
#pragma unroll
            for (int jk = 0; jk < 4; jk++) sc[jk] = (f32x4){0.f, 0.f, 0.f, 0.f};
#pragma unroll
            for (int ks = 0; ks < 2; ks++)
#pragma unroll
                for (int jk = 0; jk < 4; jk++)
                    sc[jk] = MFMA16(kf[jk][ks], qf[ks], sc[jk]);

            // static softmax: P = exp2(s*C - M0); only diagonal tile masks
            const bool needmask = (kt == qt);
            short* prow = PT + (w * 16 + lr) * 72;
#pragma unroll
            for (int jk = 0; jk < 4; jk++) {
                s16x4 pk;
#pragma unroll
                for (int r = 0; r < 4; r++) {
                    float p = exp2f(fmaf(sc[jk][r], C, -M0));
                    if (needmask) {
                        int key = kb + jk * 16 + quad * 4 + r;
                        if (key > qq) p = 0.f;
                    }
                    lsum += p;
                    pk[r] = __builtin_bit_cast(short, __float2bfloat16(p));
                }
                *reinterpret_cast<s16x4*>(prow + jk * 16 + quad * 4) = pk;
            }

            __syncthreads();   // VT + PT ready

#pragma unroll
            for (int ks = 0; ks < 2; ks++) {
                s16x8 pf = ld8s(PT + (w * 16 + lr) * 72 + ks * 32 + quad * 8);
                s16x8 vf[4];
#pragma unroll
                for (int j = 0; j < 4; j++)
                    vf[j] = ld8s(VT + (j * 16 + lr) * 72 + ks * 32 + quad * 8);
#pragma unroll
                for (int j = 0; j < 4; j++) o[j] = MFMA16(pf, vf[j], o[j]);
            }
        }

        // epilogue: finish l reduction (deferred), normalize, store
        float l = lsum;
        l += __shfl_xor(l, 16);
        l += __shfl_xor(l, 32);
#pragma unroll
        for (int r = 0; r < 4; r++) {
            float inv = 1.f / __shfl(l, quad * 4 + r);
            int t = tw + quad * 4 + r;
#pragma unroll
            for (int j = 0; j < 4; j++)
                Ob[base + (size_t)t * 1024 + j * 16 + lr] =
                    __float2bfloat16(o[j][r] * inv);
        }
    }
}

// ---------------------------------------------------------------------------
// out = A @ Wu^T + bu  (m97 structure, both operands bf16 via global_load_lds)
// ---------------------------------------------------------------------------
__global__ __launch_bounds__(256) void gemm_bias(
    const bf16* __restrict__ A, const bf16* __restrict__ Bt,
    const float* __restrict__ bias, float* __restrict__ out)
{
    __shared__ __align__(16) short lA[128 * 32];
    __shared__ __align__(16) short lB[128 * 32];

    const int tid  = threadIdx.x;
    const int lane = tid & 63;
    const int w    = tid >> 6;
    const int wr = w >> 1, wc = w & 1;
    const int lr = lane & 15, quad = lane >> 4;

    const int m0 = blockIdx.y * 128;
    const int n0 = blockIdx.x * 128;

    const int strow = w * 32 + (lane >> 2);
    const int stcol = (lane & 3) * 8;
    const bf16* agl = A  + (size_t)(m0 + strow) * EE + stcol;
    const bf16* bgl = Bt + (size_t)(n0 + strow) * EE + stcol;
    short* al = lA + (w * 2) * 512;
    short* bl = lB + (w * 2) * 512;

    f32x4 acc[4][4];
#pragma unroll
    for (int i = 0; i < 4; i++)
#pragma unroll
        for (int j = 0; j < 4; j++) acc[i][j] = (f32x4){0.f, 0.f, 0.f, 0.f};

    const short* lArd = lA + (wr * 64 + lr) * 32 + quad * 8;
    const short* lBrd = lB + (wc * 64 + lr) * 32 + quad * 8;

    for (int kt = 0; kt < EE / 32; ++kt) {
        __syncthreads();
        async16(al, agl);
        async16(al + 512, agl + 16 * EE);
        async16(bl, bgl);
        async16(bl + 512, bgl + 16 * EE);
        agl += 32;
        bgl += 32;
        __syncthreads();

        s16x8 af[4], bfr[4];
#pragma unroll
        for (int i = 0; i < 4; i++) af[i]  = ld8s(lArd + i * 16 * 32);
#pragma unroll
        for (int j = 0; j < 4; j++) bfr[j] = ld8s(lBrd + j * 16 * 32);
#pragma unroll
        for (int i = 0; i < 4; i++)
#pragma unroll
            for (int j = 0; j < 4; j++) acc[i][j] = MFMA16(af[i], bfr[j], acc[i][j]);
    }

    float bz[4];
#pragma unroll
    for (int j = 0; j < 4; j++)
        bz[j] = bias[n0 + wc * 64 + j * 16 + lr];
#pragma unroll
    for (int i = 0; i < 4; i++)
#pragma unroll
        for (int r = 0; r < 4; r++) {
            int row = m0 + wr * 64 + i * 16 + quad * 4 + r;
#pragma unroll
            for (int j = 0; j < 4; j++)
                out[(size_t)row * EE + n0 + wc * 64 + j * 16 + lr] =
                    acc[i][j][r] + bz[j];
        }
}

// ---------------------------------------------------------------------------
extern "C" void kernel_launch(void* const* d_in, const int* in_sizes, int n_in,
                              void* d_out, int out_size, void* d_ws, size_t ws_size,
                              hipStream_t stream)
{
    (void)in_sizes; (void)n_in; (void)out_size;
    const float* x   = (const float*)d_in[0];
    const float* Wq  = (const float*)d_in[1];
    const float* Wk  = (const float*)d_in[2];
    const float* Wv  = (const float*)d_in[3];
    const float* Wu  = (const float*)d_in[4];
    const float* bu  = (const float*)d_in[5];
    const float* qg  = (const float*)d_in[6];
    const float* qbt = (const float*)d_in[7];
    const float* kg  = (const float*)d_in[8];
    const float* kbt = (const float*)d_in[9];
    float* out = (float*)d_out;

    bf16* Qb  = (bf16*)d_ws;                    // 16MB (doubles as attn-out)
    bf16* Kb  = Qb  + (size_t)8192 * 1024;
    bf16* Vb  = Kb  + (size_t)8192 * 1024;
    bf16* Wqb = Vb  + (size_t)8192 * 1024;      // 2MB each
    bf16* Wkb = Wqb + (size_t)1024 * 1024;
    bf16* Wvb = Wkb + (size_t)1024 * 1024;
    bf16* Wub = Wvb + (size_t)1024 * 1024;
    bf16* xb  = Wub + (size_t)1024 * 1024;      // 16MB

    const size_t need = ((size_t)3 * 8192 * 1024 + 4 * 1024 * 1024 + 8192 * 1024) * 2;
    const bool fast = ws_size >= need;

    cvt_all<<<dim3(512, 1, fast ? 12 : 4), 256, 0, stream>>>(
        Wq, Wk, Wv, Wu, x, Wqb, Wkb, Wvb, Wub, xb);
    if (fast)
        gemm_qkv_t<0><<<dim3(8, 64, 3), 256, 0, stream>>>(
            x, xb, Wqb, Wkb, Wvb, Qb, Kb, Vb, qg, qbt, kg, kbt);
    else
        gemm_qkv_t<1><<<dim3(8, 64, 3), 256, 0, stream>>>(
            x, nullptr, Wqb, Wkb, Wvb, Qb, Kb, Vb, qg, qbt, kg, kbt);
    flash<<<dim3(16, 64), 256, 0, stream>>>(Qb, Kb, Vb, Qb);
    gemm_bias<<<dim3(8, 64), 256, 0, stream>>>(Qb, Wub, bu, out);
}

// Round 6
// 310.444 us; speedup vs baseline: 1.2400x; 1.2400x over previous
//
#include <hip/hip_runtime.h>
#include <hip/hip_bf16.h>
#include <stdint.h>
#include <stddef.h>

// SelfAttention: B=4 T=2048 E=1024 H=16 S=64, causal, q/k LayerNorm over S.
// f32 in/out; bf16 MFMA compute.
//   0) cvt_all: Wq/Wk/Wv/Wu and x f32 -> bf16 (one pass).
//   1) gemm_qkv: Q/K/V = x@W^T, fused head-LayerNorm (q,k), SCALE folded in Q.
//      m97 structure: global_load_lds width-16 staging, 128x128 tile, BK=32.
//   2) flash: causal attention, STATIC softmax (LN bound: ||q*0.125||=1,
//      ||k||=8 -> |s*log2e| <= 11.6 -> P = exp2(s*C - 12), no running max,
//      no rescale, l-sum deferred to epilogue).  128-row q-tiles, balanced
//      pairs (p,15-p) = 34 k-tiles/block, grid 8x64.  K/V double-buffered
//      register prefetch hides global latency.  Output aliases Qb.
//   3) gemm_bias: out = attn@Wu^T + bu (same m97 structure).
// Workspace: Q(=AO),K,V (48MB) + W bf16 (8MB) + xb (16MB) = 72MB (fallback
// template if ws_size < 72MB keeps the old f32-A staging).

using bf16 = __hip_bfloat16;
typedef __attribute__((ext_vector_type(8))) short s16x8;
typedef __attribute__((ext_vector_type(4))) short s16x4;
typedef __attribute__((ext_vector_type(4))) float f32x4;

#define MFMA16(a, b, c) __builtin_amdgcn_mfma_f32_16x16x32_bf16((a), (b), (c), 0, 0, 0)

static __device__ __forceinline__ s16x8 ld8(const bf16* p) {
    return *reinterpret_cast<const s16x8*>(p);
}
static __device__ __forceinline__ s16x8 ld8s(const short* p) {
    return *reinterpret_cast<const s16x8*>(p);
}
static __device__ __forceinline__ s16x8 cvt8(const float* p) {
    f32x4 u = *reinterpret_cast<const f32x4*>(p);
    f32x4 v = *reinterpret_cast<const f32x4*>(p + 4);
    s16x8 r;
#pragma unroll
    for (int e = 0; e < 4; e++) {
        r[e]     = __builtin_bit_cast(short, __float2bfloat16(u[e]));
        r[e + 4] = __builtin_bit_cast(short, __float2bfloat16(v[e]));
    }
    return r;
}

// async global(bf16)->LDS, 16B per lane; lds base must be wave-uniform.
static __device__ __forceinline__ void async16(short* lds, const bf16* g) {
    __builtin_amdgcn_global_load_lds(
        (const __attribute__((address_space(1))) unsigned int*)g,
        (__attribute__((address_space(3))) unsigned int*)lds, 16, 0, 0);
}

#define EE 1024

// ---------------------------------------------------------------------------
// f32 -> bf16: z=0..3 weights (1M each), z=4..11 x slices (8 x 1M)
// ---------------------------------------------------------------------------
__global__ __launch_bounds__(256) void cvt_all(
    const float* __restrict__ w0, const float* __restrict__ w1,
    const float* __restrict__ w2, const float* __restrict__ w3,
    const float* __restrict__ x,
    bf16* __restrict__ o0, bf16* __restrict__ o1,
    bf16* __restrict__ o2, bf16* __restrict__ o3, bf16* __restrict__ xb)
{
    const int z = blockIdx.z;
    const float* s;
    bf16* d;
    if (z < 4) {
        s = (z == 0) ? w0 : (z == 1) ? w1 : (z == 2) ? w2 : w3;
        d = (z == 0) ? o0 : (z == 1) ? o1 : (z == 2) ? o2 : o3;
    } else {
        s = x  + (size_t)(z - 4) * 1048576;
        d = xb + (size_t)(z - 4) * 1048576;
    }
    size_t i = ((size_t)blockIdx.x * 256 + threadIdx.x) * 8;
    *reinterpret_cast<s16x8*>(d + i) = cvt8(s + i);
}

// ---------------------------------------------------------------------------
// Fused QKV GEMM + head LayerNorm.  z=0:Q(+LN,*0.125) z=1:K(+LN) z=2:V
// AF32=0: A staged via global_load_lds from xb.  AF32=1: f32 cvt fallback.
// ---------------------------------------------------------------------------
template <int AF32>
__global__ __launch_bounds__(256) void gemm_qkv_t(
    const float* __restrict__ xf, const bf16* __restrict__ xb,
    const bf16* __restrict__ Wq, const bf16* __restrict__ Wk, const bf16* __restrict__ Wv,
    bf16* __restrict__ Qb, bf16* __restrict__ Kb, bf16* __restrict__ Vb,
    const float* __restrict__ qg, const float* __restrict__ qbt,
    const float* __restrict__ kg, const float* __restrict__ kbt)
{
    constexpr int SA = AF32 ? 40 : 32;
    const int z = blockIdx.z;
    const bf16* Bt = (z == 0) ? Wq : (z == 1) ? Wk : Wv;
    bf16* out      = (z == 0) ? Qb : (z == 1) ? Kb : Vb;
    const float* gamma = (z == 0) ? qg : kg;
    const float* beta  = (z == 0) ? qbt : kbt;
    const bool  ln     = (z < 2);
    const float oscale = (z == 0) ? 0.125f : 1.0f;

    __shared__ __align__(16) short lA[128 * SA];
    __shared__ __align__(16) short lB[128 * 32];

    const int tid  = threadIdx.x;
    const int lane = tid & 63;
    const int w    = tid >> 6;
    const int wr = w >> 1, wc = w & 1;
    const int lr = lane & 15, quad = lane >> 4;

    const int m0 = blockIdx.y * 128;
    const int n0 = blockIdx.x * 128;

    const int strow = w * 32 + (lane >> 2);
    const int stcol = (lane & 3) * 8;
    const bf16* bgl = Bt + (size_t)(n0 + strow) * EE + stcol;
    short* bl = lB + (w * 2) * 512;

    const bf16* agl = nullptr;
    const float* ap = nullptr;
    short* al = lA + (w * 2) * 512;
    short* lap = nullptr;
    if constexpr (AF32) {
        const int sr  = tid >> 1;
        const int sc0 = (tid & 1) << 4;
        ap  = xf + (size_t)(m0 + sr) * EE + sc0;
        lap = lA + sr * SA + sc0;
    } else {
        agl = xb + (size_t)(m0 + strow) * EE + stcol;
    }

    f32x4 acc[4][4];
#pragma unroll
    for (int i = 0; i < 4; i++)
#pragma unroll
        for (int j = 0; j < 4; j++) acc[i][j] = (f32x4){0.f, 0.f, 0.f, 0.f};

    const short* lArd = lA + (wr * 64 + lr) * SA + quad * 8;
    const short* lBrd = lB + (wc * 64 + lr) * 32 + quad * 8;

    for (int kt = 0; kt < EE / 32; ++kt) {
        if constexpr (AF32) {
            s16x8 a0 = cvt8(ap), a1 = cvt8(ap + 8);
            __syncthreads();
            *reinterpret_cast<s16x8*>(lap)     = a0;
            *reinterpret_cast<s16x8*>(lap + 8) = a1;
            async16(bl, bgl);
            async16(bl + 512, bgl + 16 * EE);
            ap += 32;
        } else {
            __syncthreads();
            async16(al, agl);
            async16(al + 512, agl + 16 * EE);
            async16(bl, bgl);
            async16(bl + 512, bgl + 16 * EE);
            agl += 32;
        }
        bgl += 32;
        __syncthreads();

        s16x8 af[4], bfr[4];
#pragma unroll
        for (int i = 0; i < 4; i++) af[i]  = ld8s(lArd + i * 16 * SA);
#pragma unroll
        for (int j = 0; j < 4; j++) bfr[j] = ld8s(lBrd + j * 16 * 32);
#pragma unroll
        for (int i = 0; i < 4; i++)
#pragma unroll
            for (int j = 0; j < 4; j++) acc[i][j] = MFMA16(af[i], bfr[j], acc[i][j]);
    }

    if (ln) {
        float g[4], bt[4];
#pragma unroll
        for (int j = 0; j < 4; j++) {
            g[j]  = gamma[j * 16 + lr];
            bt[j] = beta[j * 16 + lr];
        }
#pragma unroll
        for (int i = 0; i < 4; i++) {
#pragma unroll
            for (int r = 0; r < 4; r++) {
                float s1 = 0.f, s2 = 0.f;
#pragma unroll
                for (int j = 0; j < 4; j++) {
                    float v = acc[i][j][r];
                    s1 += v;
                    s2 += v * v;
                }
#pragma unroll
                for (int off = 1; off < 16; off <<= 1) {
                    s1 += __shfl_xor(s1, off);
                    s2 += __shfl_xor(s2, off);
                }
                float mu  = s1 * (1.f / 64.f);
                float var = s2 * (1.f / 64.f) - mu * mu;
                float rs  = rsqrtf(var + 1e-5f);
                int row = m0 + wr * 64 + i * 16 + quad * 4 + r;
#pragma unroll
                for (int j = 0; j < 4; j++) {
                    float v = ((acc[i][j][r] - mu) * rs * g[j] + bt[j]) * oscale;
                    out[(size_t)row * EE + n0 + wc * 64 + j * 16 + lr] = __float2bfloat16(v);
                }
            }
        }
    } else {
#pragma unroll
        for (int i = 0; i < 4; i++)
#pragma unroll
            for (int r = 0; r < 4; r++) {
                int row = m0 + wr * 64 + i * 16 + quad * 4 + r;
#pragma unroll
                for (int j = 0; j < 4; j++)
                    out[(size_t)row * EE + n0 + wc * 64 + j * 16 + lr] =
                        __float2bfloat16(acc[i][j][r]);
            }
    }
}

// ---------------------------------------------------------------------------
// Causal flash attention: static softmax + 128-row q-tiles + K/V register
// double-buffer prefetch.  grid = (8 pairs, 64 b*h); wave owns 32 q-rows.
// nkt = 2qt+2 is always even -> unroll-by-2 with explicit buffers.
// ---------------------------------------------------------------------------
__global__ __launch_bounds__(256, 2) void flash(
    const bf16* __restrict__ Qb, const bf16* __restrict__ Kb,
    const bf16* __restrict__ Vb, bf16* __restrict__ Ob)
{
    const int pr = blockIdx.x;
    const int bh = blockIdx.y;
    const int b = bh >> 4, h = bh & 15;
    const int tid = threadIdx.x, lane = tid & 63, w = tid >> 6;
    const int lr = lane & 15, quad = lane >> 4;
    const size_t base = (size_t)b * 2048 * 1024 + h * 64;
    const float C  = 1.44269504088896340736f;   // log2(e); 1/8 folded into Q
    const float M0 = 12.0f;                     // static max bound (LN norms)

    __shared__ __align__(16) short VT[64 * 72];   // V^T tile [s][key]
    __shared__ __align__(16) short PT[128 * 72];  // P tile   [query][key]

#pragma unroll 1
    for (int ph = 0; ph < 2; ++ph) {
        const int qt = ph ? (15 - pr) : pr;
        const int tw = qt * 128 + w * 32;

        // Q fragments (B operand: col=query=lr, k=quad*8), resident all tiles
        s16x8 qf[2][2];
#pragma unroll
        for (int i = 0; i < 2; i++)
#pragma unroll
            for (int ks = 0; ks < 2; ks++)
                qf[i][ks] = ld8(Qb + base + (size_t)(tw + i * 16 + lr) * 1024 +
                                ks * 32 + quad * 8);

        f32x4 o[2][4];
#pragma unroll
        for (int i = 0; i < 2; i++)
#pragma unroll
            for (int j = 0; j < 4; j++) o[i][j] = (f32x4){0.f, 0.f, 0.f, 0.f};
        float lsum[2] = {0.f, 0.f};

        const int nkt = 2 * qt + 2;   // even

        // prefetch tile 0 (kb=0: active for every wave)
        s16x8 va0, va1, kfa[4][2];
        s16x8 vb0, vb1, kfb[4][2];
        va0 = ld8(Vb + base + (size_t)lane * 1024 + w * 8);
        va1 = ld8(Vb + base + (size_t)lane * 1024 + w * 8 + 32);
#pragma unroll
        for (int jk = 0; jk < 4; jk++)
#pragma unroll
            for (int ks = 0; ks < 2; ks++)
                kfa[jk][ks] = ld8(Kb + base + (size_t)(jk * 16 + lr) * 1024 +
                                  ks * 32 + quad * 8);

#define FTILE(KT, V0C, V1C, KFC, V0N, V1N, KFN)                                  \
    {                                                                            \
        const int kb = (KT) * 64;                                                \
        const bool active = (kb <= tw + 31);                                     \
        __syncthreads(); /* prior iter's VT/PT reads done */                     \
        _Pragma("unroll")                                                        \
        for (int e = 0; e < 8; e++) {                                            \
            VT[(w * 8 + e) * 72 + lane]      = V0C[e];                           \
            VT[(w * 8 + 32 + e) * 72 + lane] = V1C[e];                           \
        }                                                                        \
        const int kb2 = kb + 64;                                                 \
        if (kb2 < nkt * 64) { /* prefetch next tile */                           \
            V0N = ld8(Vb + base + (size_t)(kb2 + lane) * 1024 + w * 8);          \
            V1N = ld8(Vb + base + (size_t)(kb2 + lane) * 1024 + w * 8 + 32);     \
            if (kb2 <= tw + 31) {                                                \
                _Pragma("unroll")                                                \
                for (int jk = 0; jk < 4; jk++)                                   \
                    _Pragma("unroll")                                            \
                    for (int ks = 0; ks < 2; ks++)                               \
                        KFN[jk][ks] = ld8(Kb + base +                            \
                            (size_t)(kb2 + jk * 16 + lr) * 1024 +                \
                            ks * 32 + quad * 8);                                 \
            }                                                                    \
        }                                                                        \
        if (active) {                                                            \
            f32x4 sc[2][4];                                                      \
            _Pragma("unroll")                                                    \
            for (int i = 0; i < 2; i++)                                          \
                _Pragma("unroll")                                                \
                for (int jk = 0; jk < 4; jk++)                                   \
                    sc[i][jk] = (f32x4){0.f, 0.f, 0.f, 0.f};                     \
            _Pragma("unroll")                                                    \
            for (int ks = 0; ks < 2; ks++)                                       \
                _Pragma("unroll")                                                \
                for (int i = 0; i < 2; i++)                                      \
                    _Pragma("unroll")                                            \
                    for (int jk = 0; jk < 4; jk++)                               \
                        sc[i][jk] = MFMA16(KFC[jk][ks], qf[i][ks], sc[i][jk]);   \
            const bool needmask = (kb + 63 > tw);                                \
            _Pragma("unroll")                                                    \
            for (int i = 0; i < 2; i++) {                                        \
                const int qq = tw + i * 16 + lr;                                 \
                short* prow = PT + (w * 32 + i * 16 + lr) * 72;                  \
                _Pragma("unroll")                                                \
                for (int jk = 0; jk < 4; jk++) {                                 \
                    s16x4 pk;                                                    \
                    _Pragma("unroll")                                            \
                    for (int r = 0; r < 4; r++) {                                \
                        float p = exp2f(fmaf(sc[i][jk][r], C, -M0));             \
                        if (needmask && (kb + jk * 16 + quad * 4 + r > qq))      \
                            p = 0.f;                                             \
                        lsum[i] += p;                                            \
                        pk[r] = __builtin_bit_cast(short, __float2bfloat16(p));  \
                    }                                                            \
                    *reinterpret_cast<s16x4*>(prow + jk * 16 + quad * 4) = pk;   \
                }                                                                \
            }                                                                    \
        }                                                                        \
        __syncthreads(); /* VT + PT ready */                                     \
        if (active) {                                                            \
            _Pragma("unroll")                                                    \
            for (int ks = 0; ks < 2; ks++) {                                     \
                s16x8 pf[2], vf[4];                                              \
                _Pragma("unroll")                                                \
                for (int i = 0; i < 2; i++)                                      \
                    pf[i] = ld8s(PT + (w * 32 + i * 16 + lr) * 72 +              \
                                 ks * 32 + quad * 8);                            \
                _Pragma("unroll")                                                \
                for (int j = 0; j < 4; j++)                                      \
                    vf[j] = ld8s(VT + (j * 16 + lr) * 72 + ks * 32 + quad * 8);  \
                _Pragma("unroll")                                                \
                for (int i = 0; i < 2; i++)                                      \
                    _Pragma("unroll")                                            \
                    for (int j = 0; j < 4; j++)                                  \
                        o[i][j] = MFMA16(pf[i], vf[j], o[i][j]);                 \
            }                                                                    \
        }                                                                        \
    }

#pragma unroll 1
        for (int kt = 0; kt < nkt; kt += 2) {
            FTILE(kt,     va0, va1, kfa, vb0, vb1, kfb)
            FTILE(kt + 1, vb0, vb1, kfb, va0, va1, kfa)
        }
#undef FTILE

        // epilogue: finish l reduction (deferred), normalize, store
#pragma unroll
        for (int i = 0; i < 2; i++) {
            float l = lsum[i];
            l += __shfl_xor(l, 16);
            l += __shfl_xor(l, 32);
#pragma unroll
            for (int r = 0; r < 4; r++) {
                float inv = 1.f / __shfl(l, quad * 4 + r);
                int t = tw + i * 16 + quad * 4 + r;
#pragma unroll
                for (int j = 0; j < 4; j++)
                    Ob[base + (size_t)t * 1024 + j * 16 + lr] =
                        __float2bfloat16(o[i][j][r] * inv);
            }
        }
    }
}

// ---------------------------------------------------------------------------
// out = A @ Wu^T + bu  (m97 structure, both operands bf16 via global_load_lds)
// ---------------------------------------------------------------------------
__global__ __launch_bounds__(256) void gemm_bias(
    const bf16* __restrict__ A, const bf16* __restrict__ Bt,
    const float* __restrict__ bias, float* __restrict__ out)
{
    __shared__ __align__(16) short lA[128 * 32];
    __shared__ __align__(16) short lB[128 * 32];

    const int tid  = threadIdx.x;
    const int lane = tid & 63;
    const int w    = tid >> 6;
    const int wr = w >> 1, wc = w & 1;
    const int lr = lane & 15, quad = lane >> 4;

    const int m0 = blockIdx.y * 128;
    const int n0 = blockIdx.x * 128;

    const int strow = w * 32 + (lane >> 2);
    const int stcol = (lane & 3) * 8;
    const bf16* agl = A  + (size_t)(m0 + strow) * EE + stcol;
    const bf16* bgl = Bt + (size_t)(n0 + strow) * EE + stcol;
    short* al = lA + (w * 2) * 512;
    short* bl = lB + (w * 2) * 512;

    f32x4 acc[4][4];
#pragma unroll
    for (int i = 0; i < 4; i++)
#pragma unroll
        for (int j = 0; j < 4; j++) acc[i][j] = (f32x4){0.f, 0.f, 0.f, 0.f};

    const short* lArd = lA + (wr * 64 + lr) * 32 + quad * 8;
    const short* lBrd = lB + (wc * 64 + lr) * 32 + quad * 8;

    for (int kt = 0; kt < EE / 32; ++kt) {
        __syncthreads();
        async16(al, agl);
        async16(al + 512, agl + 16 * EE);
        async16(bl, bgl);
        async16(bl + 512, bgl + 16 * EE);
        agl += 32;
        bgl += 32;
        __syncthreads();

        s16x8 af[4], bfr[4];
#pragma unroll
        for (int i = 0; i < 4; i++) af[i]  = ld8s(lArd + i * 16 * 32);
#pragma unroll
        for (int j = 0; j < 4; j++) bfr[j] = ld8s(lBrd + j * 16 * 32);
#pragma unroll
        for (int i = 0; i < 4; i++)
#pragma unroll
            for (int j = 0; j < 4; j++) acc[i][j] = MFMA16(af[i], bfr[j], acc[i][j]);
    }

    float bz[4];
#pragma unroll
    for (int j = 0; j < 4; j++)
        bz[j] = bias[n0 + wc * 64 + j * 16 + lr];
#pragma unroll
    for (int i = 0; i < 4; i++)
#pragma unroll
        for (int r = 0; r < 4; r++) {
            int row = m0 + wr * 64 + i * 16 + quad * 4 + r;
#pragma unroll
            for (int j = 0; j < 4; j++)
                out[(size_t)row * EE + n0 + wc * 64 + j * 16 + lr] =
                    acc[i][j][r] + bz[j];
        }
}

// ---------------------------------------------------------------------------
extern "C" void kernel_launch(void* const* d_in, const int* in_sizes, int n_in,
                              void* d_out, int out_size, void* d_ws, size_t ws_size,
                              hipStream_t stream)
{
    (void)in_sizes; (void)n_in; (void)out_size;
    const float* x   = (const float*)d_in[0];
    const float* Wq  = (const float*)d_in[1];
    const float* Wk  = (const float*)d_in[2];
    const float* Wv  = (const float*)d_in[3];
    const float* Wu  = (const float*)d_in[4];
    const float* bu  = (const float*)d_in[5];
    const float* qg  = (const float*)d_in[6];
    const float* qbt = (const float*)d_in[7];
    const float* kg  = (const float*)d_in[8];
    const float* kbt = (const float*)d_in[9];
    float* out = (float*)d_out;

    bf16* Qb  = (bf16*)d_ws;                    // 16MB (doubles as attn-out)
    bf16* Kb  = Qb  + (size_t)8192 * 1024;
    bf16* Vb  = Kb  + (size_t)8192 * 1024;
    bf16* Wqb = Vb  + (size_t)8192 * 1024;      // 2MB each
    bf16* Wkb = Wqb + (size_t)1024 * 1024;
    bf16* Wvb = Wkb + (size_t)1024 * 1024;
    bf16* Wub = Wvb + (size_t)1024 * 1024;
    bf16* xb  = Wub + (size_t)1024 * 1024;      // 16MB

    const size_t need = ((size_t)3 * 8192 * 1024 + 4 * 1024 * 1024 + 8192 * 1024) * 2;
    const bool fast = ws_size >= need;

    cvt_all<<<dim3(512, 1, fast ? 12 : 4), 256, 0, stream>>>(
        Wq, Wk, Wv, Wu, x, Wqb, Wkb, Wvb, Wub, xb);
    if (fast)
        gemm_qkv_t<0><<<dim3(8, 64, 3), 256, 0, stream>>>(
            x, xb, Wqb, Wkb, Wvb, Qb, Kb, Vb, qg, qbt, kg, kbt);
    else
        gemm_qkv_t<1><<<dim3(8, 64, 3), 256, 0, stream>>>(
            x, nullptr, Wqb, Wkb, Wvb, Qb, Kb, Vb, qg, qbt, kg, kbt);
    flash<<<dim3(8, 64), 256, 0, stream>>>(Qb, Kb, Vb, Qb);
    gemm_bias<<<dim3(8, 64), 256, 0, stream>>>(Qb, Wub, bu, out);
}